// Round 11
// baseline (371.536 us; speedup 1.0000x reference)
//
#include <hip/hip_runtime.h>

#define N_NODES 50000
#define N_EDGES 800000
#define NREL 8
#define NB8 (N_NODES * NREL)      // 400000
#define SCAN_T 12500              // NB8 / 32
#define KSTEPS 36                 // 1152 / 32
#define A_STRIDE 1160             // shorts per LDS row
#define NTILES32 ((N_NODES + 31) / 32)   // 1563
#define BB 104                    // build blocks (spin cost ~ O(blocks): keep small)

typedef __attribute__((ext_vector_type(8))) short short8;
typedef __attribute__((ext_vector_type(4))) float f32x4;
typedef __attribute__((ext_vector_type(2))) float f32x2;

__device__ __forceinline__ unsigned short f2bf(float v) {
    union { float f; unsigned int u; } c; c.f = v;
    return (unsigned short)((c.u + 0x7FFFu + ((c.u >> 16) & 1u)) >> 16);
}
__device__ __forceinline__ float bfhi2f(unsigned int u) {
    union { unsigned int u; float f; } c; c.u = u & 0xFFFF0000u; return c.f;
}
__device__ __forceinline__ float bflo2f(unsigned int u) {
    union { unsigned int u; float f; } c; c.u = u << 16; return c.f;
}
__device__ __forceinline__ unsigned fbits(float v) {
    union { float f; unsigned u; } c; c.f = v; return c.u;
}
__device__ __forceinline__ float bitsf(int u) {
    union { int i; float f; } c; c.i = u; return c.f;
}

// ---------------------------------------------------------------------------
// Fused prep: zero cnt + flags + cast X to bf16 + pack 3 weight sets
// ---------------------------------------------------------------------------
#define PREP_Z   (NB8 / 4)
#define PREP_X   (N_NODES * 32)
#define PREP_P   (8 * KSTEPS * 64)
#define PREP_P2  (1 * KSTEPS * 64)
#define PREP_TOTAL (PREP_Z + PREP_X + 2 * PREP_P + PREP_P2)

__device__ __forceinline__ void pack_one(int idx, const float* __restrict__ root,
                                         const float* __restrict__ W,
                                         unsigned short* __restrict__ Wpack, int FOUT) {
    int lane = idx & 63;
    int ks = (idx >> 6) % KSTEPS;
    int ct = idx / (KSTEPS * 64);
    int kbase = ks * 32 + (lane >> 4) * 8;
    int col = ct * 16 + (lane & 15);
    union { unsigned short us[8]; uint4 v; } u;
#pragma unroll
    for (int j = 0; j < 8; j++) {
        int k = kbase + j;
        float val = (k < 128) ? root[(size_t)k * FOUT + col]
                              : W[(size_t)(k - 128) * FOUT + col];
        u.us[j] = f2bf(val);
    }
    ((uint4*)Wpack)[idx] = u.v;
}

__global__ void prep_kernel(const float* __restrict__ X, unsigned int* __restrict__ Xb2,
                            const float* __restrict__ r0, const float* __restrict__ w0,
                            unsigned short* __restrict__ Wp0,
                            const float* __restrict__ r1, const float* __restrict__ w1,
                            unsigned short* __restrict__ Wp1,
                            const float* __restrict__ r2, const float* __restrict__ w2,
                            unsigned short* __restrict__ Wp2,
                            int* __restrict__ cnt, int* __restrict__ flags) {
    int t = blockIdx.x * blockDim.x + threadIdx.x;
    if (blockIdx.x == 0 && threadIdx.x < 8) flags[threadIdx.x] = 0;
    if (t < PREP_Z) { ((int4*)cnt)[t] = make_int4(0, 0, 0, 0); return; }
    t -= PREP_Z;
    if (t < PREP_X) {
        float4 v = ((const float4*)X)[t];
        unsigned int p0 = (unsigned int)f2bf(v.x) | ((unsigned int)f2bf(v.y) << 16);
        unsigned int p1 = (unsigned int)f2bf(v.z) | ((unsigned int)f2bf(v.w) << 16);
        ((uint2*)Xb2)[t] = make_uint2(p0, p1);
        return;
    }
    t -= PREP_X;
    if (t < PREP_P) { pack_one(t, r0, w0, Wp0, 128); return; }
    t -= PREP_P;
    if (t < PREP_P) { pack_one(t, r1, w1, Wp1, 128); return; }
    t -= PREP_P;
    if (t < PREP_P2) pack_one(t, r2, w2, Wp2, 16);
}

// ---------------------------------------------------------------------------
// Fused CSR build in ONE dispatch @ 104 blocks. Spin barriers cost
// ~O(blocks x atomic-latency) serialized on one line (R9: 512 blocks x 4
// barriers = ~170us). s_sleep backoff + 104 blocks keeps each ~2-3us.
// ---------------------------------------------------------------------------
__device__ __forceinline__ void sleep_wait(int* flag, int target) {
    while (atomicAdd(flag, 0) < target) __builtin_amdgcn_s_sleep(2);
    __threadfence();
}
__device__ __forceinline__ void gbar(int* flag, int n, int tid) {
    __syncthreads();
    if (tid == 0) {
        __threadfence();
        atomicAdd(flag, 1);
        sleep_wait(flag, n);
    }
    __syncthreads();
}

__global__ __launch_bounds__(256) void build_kernel(
    const int* __restrict__ ei, const int* __restrict__ et,
    int* __restrict__ cnt, int* __restrict__ rank,
    int* __restrict__ tsum, int* __restrict__ toff,
    int* __restrict__ rs8, float* __restrict__ inv8,
    unsigned short* __restrict__ csr_src, int* __restrict__ flags)
{
    int tid = threadIdx.x;
    int gid = blockIdx.x * 256 + tid;
    const int T = BB * 256;

    // P0: rank (one atomic pass)
    for (int e = gid; e < N_EDGES; e += T) {
        int d = ei[N_EDGES + e];
        int ty = et[e];
        rank[e] = atomicAdd(&cnt[d * NREL + ty], 1);
    }
    gbar(&flags[0], BB, tid);

    // P1: per-32 partial sums
    for (int g = gid; g < SCAN_T; g += T) {
        const int4* p = (const int4*)(cnt + (size_t)g * 32);
        int s = 0;
#pragma unroll
        for (int j = 0; j < 8; j++) {
            int4 v = p[j];
            s += v.x + v.y + v.z + v.w;
        }
        tsum[g] = s;
    }
    gbar(&flags[1], BB, tid);

    // P2: block 0 scans the 12500 partials
    if (blockIdx.x == 0) {
        __shared__ int part[256];
        const int C = (SCAN_T + 255) / 256;            // 49
        int n0 = tid * C, n1 = n0 + C; if (n1 > SCAN_T) n1 = SCAN_T;
        int s = 0;
        for (int n = n0; n < n1; n++) s += tsum[n];
        part[tid] = s;
        __syncthreads();
        for (int off = 1; off < 256; off <<= 1) {
            int v = (tid >= off) ? part[tid - off] : 0;
            __syncthreads();
            part[tid] += v;
            __syncthreads();
        }
        int run = (tid > 0) ? part[tid - 1] : 0;
        for (int n = n0; n < n1; n++) { toff[n] = run; run += tsum[n]; }
        __threadfence();
        __syncthreads();
        if (tid == 0) atomicAdd(&flags[2], 1);
    }
    if (tid == 0) sleep_wait(&flags[2], 1);
    __syncthreads();

    // P3: expand to per-(node,rel) offsets + inverse-count table
    for (int g = gid; g < SCAN_T; g += T) {
        int run = toff[g];
        int base = g * 32;
#pragma unroll 4
        for (int j = 0; j < 32; j++) {
            int c = cnt[base + j];
            rs8[base + j] = run;
            inv8[base + j] = 1.0f / (float)(c > 0 ? c : 1);
            run += c;
        }
    }
    if (gid == 0) rs8[NB8] = N_EDGES;
    gbar(&flags[3], BB, tid);

    // P4: place (sorted by (dst, rel)); ei/et L2-warm from P0
    for (int e = gid; e < N_EDGES; e += T) {
        int s = ei[e];
        int d = ei[N_EDGES + e];
        int ty = et[e];
        csr_src[rs8[d * NREL + ty] + rank[e]] = (unsigned short)s;
    }
}

// ---------------------------------------------------------------------------
// Fused layer, 32-node tiles, 1024 threads, 2 blocks/CU.
// Phase A: 2 nodes/wave as one 16-segment stream with DOUBLE-BUFFERED gather
// batches (issue batch B's loads before accumulating batch A) — one exposed
// latency per wave, remainder pipelined.
// Phase B: wave = (half, ct) MFMA GEMM.
// ---------------------------------------------------------------------------
template <int FOUT, bool RELU>
__global__ __launch_bounds__(1024, 8) void layer_kernel(
    const unsigned int* __restrict__ Xb2,        // [N][64] bf16 dword pairs
    const int* __restrict__ rs8,                 // [NB8+1]
    const float* __restrict__ inv8,              // [NB8] 1/max(cnt,1)
    const unsigned short* __restrict__ csr_src,  // [E] src ids sorted by (dst,rel)
    const unsigned short* __restrict__ Wpack,    // [NCT][36][64][8]
    const float* __restrict__ bias,
    void* __restrict__ Yout)
{
    __shared__ __align__(16) unsigned short Abuf[32][A_STRIDE];   // 74,240 B

    int tid = threadIdx.x;
    int wave = tid >> 6, lane = tid & 63;
    int l15 = lane & 15;
    int node0 = blockIdx.x * 32;

    // ---------------- Phase A
    {
        int gn0 = node0 + wave * 2;
        unsigned int* row0 = (unsigned int*)&Abuf[wave * 2][0];
        unsigned int* row1 = (unsigned int*)&Abuf[wave * 2 + 1][0];

        int bl = lane <= 16 ? lane : 16;
        int bidx = gn0 * 8 + bl; if (bidx > NB8) bidx = NB8;       // tail clamp
        int bv = rs8[bidx];                          // lanes 0..16: segment bounds
        int iidx = gn0 * 8 + l15; if (iidx > NB8 - 1) iidx = NB8 - 1;
        int invi = ((const int*)inv8)[iidx];         // lanes 0..15: inv counts
        unsigned sidx0 = (unsigned)(gn0 < N_NODES - 1 ? gn0 : N_NODES - 1);
        unsigned int self0 = Xb2[(sidx0 << 6) | lane];
        unsigned int self1 = Xb2[((sidx0 + 1) << 6) | lane];

        int e     = __builtin_amdgcn_readlane(bv, 0);
        int e_end = __builtin_amdgcn_readlane(bv, 16);

        row0[lane] = self0;
        row1[lane] = self1;

        int r = 0;                                    // segment 0..15
        int be = __builtin_amdgcn_readlane(bv, 1);
        f32x2 av = (f32x2){0.f, 0.f};

#define FLUSH_R()                                                              \
        do {                                                                   \
            float iv_ = bitsf(__builtin_amdgcn_readlane(invi, r));             \
            unsigned ux_ = fbits(av.x * iv_) + 0x8000u;                        \
            unsigned uy_ = fbits(av.y * iv_) + 0x8000u;                        \
            unsigned pk_ = __builtin_amdgcn_perm(uy_, ux_, 0x07060302u);       \
            unsigned int* rw_ = (r < 8) ? row0 : row1;                         \
            rw_[(1 + (r & 7)) * 64 + lane] = pk_;                              \
            av = (f32x2){0.f, 0.f}; r++;                                       \
            be = __builtin_amdgcn_readlane(bv, r + 1 <= 16 ? r + 1 : 16);      \
        } while (0)

        if (e < e_end) {
            int e1m = e_end - 1;
            int ma = e + lane; if (ma > e1m) ma = e1m;
            unsigned int mv = csr_src[ma];             // 64-wide meta window
            int wbase = e;

            unsigned int xpA[16], xpB[16];

            auto issue = [&](unsigned int (&xp)[16], int epos) {
                int koff = epos - wbase;               // always multiple of 16
                if (koff == 64) {                      // window exhausted
                    int mb = epos + lane; if (mb > e1m) mb = e1m;
                    mv = csr_src[mb];
                    wbase = epos;
                    koff = 0;
                }
#pragma unroll
                for (int k = 0; k < 16; k++) {
                    int sck = __builtin_amdgcn_readlane((int)mv, koff + k);
                    xp[k] = Xb2[((unsigned)sck << 6) | lane];
                }
            };
            auto accum = [&](unsigned int (&xp)[16], int epos, int bn) {
#pragma unroll
                for (int k = 0; k < 16; k++) {
                    if (k < bn) {                      // bn is wave-uniform
                        int ec = epos + k;
                        while (ec >= be) FLUSH_R();
                        av += (f32x2){bflo2f(xp[k]), bfhi2f(xp[k])};
                    }
                }
            };

            int bnA = e_end - e; if (bnA > 16) bnA = 16;
            issue(xpA, e);
            while (true) {
                int eB = e + bnA;
                int bnB = e_end - eB; if (bnB > 16) bnB = 16;
                if (bnB > 0) issue(xpB, eB);           // loads in flight over accum
                accum(xpA, e, bnA);
                e = eB;
                if (bnB <= 0) break;
                int eA = e + bnB;
                bnA = e_end - eA; if (bnA > 16) bnA = 16;
                if (bnA > 0) issue(xpA, eA);
                accum(xpB, e, bnB);
                e = eA;
                if (bnA <= 0) break;
            }
        }
        while (r < 16) FLUSH_R();
#undef FLUSH_R
    }
    __syncthreads();

    // ---------------- Phase B
    int quad = lane >> 4, l16 = lane & 15;
    if constexpr (FOUT == 128) {
        int ct = wave & 7;
        int half = wave >> 3;
        int node0h = node0 + half * 16;
        f32x4 acc = (f32x4){0.f, 0.f, 0.f, 0.f};
        const unsigned short* arow = &Abuf[half * 16 + l16][0];
        for (int ks = 0; ks < KSTEPS; ks++) {
            short8 b = *(const short8*)(Wpack + (((size_t)ct * KSTEPS + ks) * 64 + lane) * 8);
            short8 a = *(const short8*)(arow + ks * 32 + quad * 8);
            acc = __builtin_amdgcn_mfma_f32_16x16x32_bf16(a, b, acc, 0, 0, 0);
        }
        unsigned short* Yb = (unsigned short*)Yout;
        int h = ct * 16 + l16;
        float bvs = bias[h];
#pragma unroll
        for (int r4 = 0; r4 < 4; r4++) {
            int node = node0h + quad * 4 + r4;
            if (node < N_NODES) {
                float v = acc[r4] + bvs;
                if (RELU) v = v > 0.f ? v : 0.f;
                Yb[(size_t)node * 128 + h] = f2bf(v);
            }
        }
    } else {
        // FOUT == 16: per half, 8-way K-split + LDS reduce (red aliases Abuf)
        int half = wave >> 3, w8 = wave & 7;
        int ks0 = w8 * 4 + (w8 < 4 ? w8 : 4);
        int ksn = (w8 < 4) ? 5 : 4;
        f32x4 acc = (f32x4){0.f, 0.f, 0.f, 0.f};
        const unsigned short* arow = &Abuf[half * 16 + l16][0];
        for (int ks = ks0; ks < ks0 + ksn; ks++) {
            short8 b = *(const short8*)(Wpack + ((size_t)ks * 64 + lane) * 8);
            short8 a = *(const short8*)(arow + ks * 32 + quad * 8);
            acc = __builtin_amdgcn_mfma_f32_16x16x32_bf16(a, b, acc, 0, 0, 0);
        }
        __syncthreads();
        float* red = (float*)&Abuf[0][0];              // [2][8][64][4] = 16 KB
#pragma unroll
        for (int r4 = 0; r4 < 4; r4++)
            red[(((half * 8 + w8) * 64 + lane) << 2) + r4] = acc[r4];
        __syncthreads();
        if (tid < 512) {
            int half2 = tid >> 8, reg = (tid >> 6) & 3, l = tid & 63;
            float s = 0.f;
#pragma unroll
            for (int w = 0; w < 8; w++)
                s += red[(((half2 * 8 + w) * 64 + l) << 2) + reg];
            int node = node0 + half2 * 16 + ((l >> 4) << 2) + reg;
            int h = l & 15;
            if (node < N_NODES) {
                float v = s + bias[h];
                if (RELU) v = v > 0.f ? v : 0.f;
                ((float*)Yout)[(size_t)node * 16 + h] = v;
            }
        }
    }
}

// ---------------------------------------------------------------------------
extern "C" void kernel_launch(void* const* d_in, const int* in_sizes, int n_in,
                              void* d_out, int out_size, void* d_ws, size_t ws_size,
                              hipStream_t stream) {
    const float* x  = (const float*)d_in[0];
    const int*   ei = (const int*)d_in[1];
    const int*   et = (const int*)d_in[2];
    const float* w0 = (const float*)d_in[3];
    const float* r0 = (const float*)d_in[4];
    const float* b0 = (const float*)d_in[5];
    const float* w1 = (const float*)d_in[6];
    const float* r1 = (const float*)d_in[7];
    const float* b1 = (const float*)d_in[8];
    const float* w2 = (const float*)d_in[9];
    const float* r2 = (const float*)d_in[10];
    const float* b2 = (const float*)d_in[11];

    char* wsp = (char*)d_ws;
    size_t off = 0;
    auto alloc = [&](size_t bytes) -> void* {
        void* p = wsp + off;
        off += (bytes + 255) & ~(size_t)255;
        return p;
    };

    int* cnt    = (int*)alloc((size_t)NB8 * 4);
    int* rs8    = (int*)alloc(((size_t)NB8 + 1) * 4);
    float* inv8 = (float*)alloc((size_t)NB8 * 4);
    int* rank   = (int*)alloc((size_t)N_EDGES * 4);
    int* tsum   = (int*)alloc((size_t)SCAN_T * 4);
    int* toff   = (int*)alloc((size_t)SCAN_T * 4);
    int* flags  = (int*)alloc(8 * 4);
    unsigned short* csr_src = (unsigned short*)alloc((size_t)N_EDGES * 2);
    unsigned short* Wp0 = (unsigned short*)alloc((size_t)8 * KSTEPS * 64 * 8 * 2);
    unsigned short* Wp1 = (unsigned short*)alloc((size_t)8 * KSTEPS * 64 * 8 * 2);
    unsigned short* Wp2 = (unsigned short*)alloc((size_t)1 * KSTEPS * 64 * 8 * 2);
    unsigned int* Xb = (unsigned int*)alloc((size_t)N_NODES * 64 * 4);
    unsigned int* H0 = (unsigned int*)alloc((size_t)N_NODES * 64 * 4);
    unsigned int* H1 = (unsigned int*)alloc((size_t)N_NODES * 64 * 4);

    prep_kernel<<<dim3((PREP_TOTAL + 255) / 256), dim3(256), 0, stream>>>(
        x, Xb, r0, w0, Wp0, r1, w1, Wp1, r2, w2, Wp2, cnt, flags);
    build_kernel<<<dim3(BB), dim3(256), 0, stream>>>(
        ei, et, cnt, rank, tsum, toff, rs8, inv8, csr_src, flags);

    layer_kernel<128, true ><<<dim3(NTILES32), dim3(1024), 0, stream>>>(
        Xb, rs8, inv8, csr_src, Wp0, b0, (void*)H0);
    layer_kernel<128, true ><<<dim3(NTILES32), dim3(1024), 0, stream>>>(
        H0, rs8, inv8, csr_src, Wp1, b1, (void*)H1);
    layer_kernel<16, false><<<dim3(NTILES32), dim3(1024), 0, stream>>>(
        H1, rs8, inv8, csr_src, Wp2, b2, d_out);
}

// Round 12
// 336.060 us; speedup vs baseline: 1.1056x; 1.1056x over previous
//
#include <hip/hip_runtime.h>

#define N_NODES 50000
#define N_EDGES 800000
#define NREL 8
#define NB8 (N_NODES * NREL)      // 400000
#define SCAN_T 12500              // NB8 / 32
#define KSTEPS 36                 // 1152 / 32
#define A_STRIDE 1160             // shorts per LDS row (580 dw, %32==4 -> 2-way=free)
#define NTILES32 ((N_NODES + 31) / 32)   // 1563

typedef __attribute__((ext_vector_type(8))) short short8;
typedef __attribute__((ext_vector_type(4))) float f32x4;
typedef __attribute__((ext_vector_type(2))) float f32x2;

__device__ __forceinline__ unsigned short f2bf(float v) {
    union { float f; unsigned int u; } c; c.f = v;
    return (unsigned short)((c.u + 0x7FFFu + ((c.u >> 16) & 1u)) >> 16);
}
__device__ __forceinline__ float bfhi2f(unsigned int u) {
    union { unsigned int u; float f; } c; c.u = u & 0xFFFF0000u; return c.f;
}
__device__ __forceinline__ float bflo2f(unsigned int u) {
    union { unsigned int u; float f; } c; c.u = u << 16; return c.f;
}
__device__ __forceinline__ unsigned fbits(float v) {
    union { float f; unsigned u; } c; c.f = v; return c.u;
}
__device__ __forceinline__ float bitsf(int u) {
    union { int i; float f; } c; c.i = u; return c.f;
}

// ---------------------------------------------------------------------------
// Fused prep (cast X + pack W) || rank (atomic pass) in ONE dispatch.
// cnt+flags zeroed by a preceding hipMemsetAsync. Rank blocks come FIRST so
// the latency-bound atomic pass starts immediately; prep's BW-bound stream
// fills the gaps. (R9/R11 lesson: E-passes need full parallelism; fusing via
// spin barriers loses either way — so scan stays a separate 49-block kernel.)
// ---------------------------------------------------------------------------
#define PREP_X   (N_NODES * 32)
#define PREP_P   (8 * KSTEPS * 64)
#define PREP_P2  (1 * KSTEPS * 64)
#define PREP_TOT (PREP_X + 2 * PREP_P + PREP_P2)
#define RANK_BLK ((N_EDGES + 255) / 256)     // 3125
#define PREP_BLK ((PREP_TOT + 255) / 256)    // 6403

__device__ __forceinline__ void pack_one(int idx, const float* __restrict__ root,
                                         const float* __restrict__ W,
                                         unsigned short* __restrict__ Wpack, int FOUT) {
    int lane = idx & 63;
    int ks = (idx >> 6) % KSTEPS;
    int ct = idx / (KSTEPS * 64);
    int kbase = ks * 32 + (lane >> 4) * 8;
    int col = ct * 16 + (lane & 15);
    union { unsigned short us[8]; uint4 v; } u;
#pragma unroll
    for (int j = 0; j < 8; j++) {
        int k = kbase + j;
        float val = (k < 128) ? root[(size_t)k * FOUT + col]
                              : W[(size_t)(k - 128) * FOUT + col];
        u.us[j] = f2bf(val);
    }
    ((uint4*)Wpack)[idx] = u.v;
}

__global__ void prep_rank_kernel(
    const int* __restrict__ ei, const int* __restrict__ et,
    int* __restrict__ cnt, int* __restrict__ rank,
    const float* __restrict__ X, unsigned int* __restrict__ Xb2,
    const float* __restrict__ r0, const float* __restrict__ w0, unsigned short* __restrict__ Wp0,
    const float* __restrict__ r1, const float* __restrict__ w1, unsigned short* __restrict__ Wp1,
    const float* __restrict__ r2, const float* __restrict__ w2, unsigned short* __restrict__ Wp2)
{
    int b = blockIdx.x;
    if (b < RANK_BLK) {
        int e = b * 256 + threadIdx.x;
        if (e < N_EDGES) {
            int d = ei[N_EDGES + e];
            int ty = et[e];
            rank[e] = atomicAdd(&cnt[d * NREL + ty], 1);
        }
        return;
    }
    int t = (b - RANK_BLK) * 256 + threadIdx.x;
    if (t < PREP_X) {
        float4 v = ((const float4*)X)[t];
        unsigned int p0 = (unsigned int)f2bf(v.x) | ((unsigned int)f2bf(v.y) << 16);
        unsigned int p1 = (unsigned int)f2bf(v.z) | ((unsigned int)f2bf(v.w) << 16);
        ((uint2*)Xb2)[t] = make_uint2(p0, p1);
        return;
    }
    t -= PREP_X;
    if (t < PREP_P) { pack_one(t, r0, w0, Wp0, 128); return; }
    t -= PREP_P;
    if (t < PREP_P) { pack_one(t, r1, w1, Wp1, 128); return; }
    t -= PREP_P;
    if (t < PREP_P2) pack_one(t, r2, w2, Wp2, 16);
}

// ---------------------------------------------------------------------------
// Fused 3-stage scan @ 49 blocks (R8-proven): spin cost ~O(blocks), keep small.
// ---------------------------------------------------------------------------
#define SCAN_BLOCKS 49
__global__ __launch_bounds__(256) void scanABC_kernel(
    const int* __restrict__ cnt, int* __restrict__ tsum, int* __restrict__ toff,
    int* __restrict__ rs8, float* __restrict__ inv8, int* __restrict__ flags) {
    int tid = threadIdx.x;
    int gstride = SCAN_BLOCKS * 256;
    for (int g = blockIdx.x * 256 + tid; g < SCAN_T; g += gstride) {
        const int4* p = (const int4*)(cnt + (size_t)g * 32);
        int s = 0;
#pragma unroll
        for (int j = 0; j < 8; j++) {
            int4 v = p[j];
            s += v.x + v.y + v.z + v.w;
        }
        tsum[g] = s;
    }
    __threadfence();
    __syncthreads();
    if (tid == 0) atomicAdd(&flags[0], 1);
    if (blockIdx.x == 0) {
        __shared__ int part[256];
        if (tid == 0) { while (atomicAdd(&flags[0], 0) < SCAN_BLOCKS) {} __threadfence(); }
        __syncthreads();
        const int C = (SCAN_T + 255) / 256;            // 49
        int n0 = tid * C, n1 = n0 + C; if (n1 > SCAN_T) n1 = SCAN_T;
        int s = 0;
        for (int n = n0; n < n1; n++) s += tsum[n];
        part[tid] = s;
        __syncthreads();
        for (int off = 1; off < 256; off <<= 1) {
            int v = (tid >= off) ? part[tid - off] : 0;
            __syncthreads();
            part[tid] += v;
            __syncthreads();
        }
        int run = (tid > 0) ? part[tid - 1] : 0;
        for (int n = n0; n < n1; n++) { toff[n] = run; run += tsum[n]; }
        __threadfence();
        __syncthreads();
        if (tid == 0) atomicAdd(&flags[1], 1);
    }
    if (tid == 0) { while (atomicAdd(&flags[1], 0) < 1) {} __threadfence(); }
    __syncthreads();
    for (int g = blockIdx.x * 256 + tid; g < SCAN_T; g += gstride) {
        int run = toff[g];
        int base = g * 32;
#pragma unroll 4
        for (int j = 0; j < 32; j++) {
            int c = cnt[base + j];
            rs8[base + j] = run;
            inv8[base + j] = 1.0f / (float)(c > 0 ? c : 1);
            run += c;
        }
    }
    if (blockIdx.x == 0 && tid == 0) rs8[NB8] = N_EDGES;
}

__global__ void place_kernel(const int* __restrict__ ei, const int* __restrict__ et,
                             const int* __restrict__ rank, const int* __restrict__ rs8,
                             unsigned short* __restrict__ csr_src, int E) {
    int e = blockIdx.x * blockDim.x + threadIdx.x;
    if (e >= E) return;
    int s = ei[e];
    int d = ei[E + e];
    int t = et[e];
    csr_src[rs8[d * NREL + t] + rank[e]] = (unsigned short)s;
}

// ---------------------------------------------------------------------------
// Fused layer, 32-node tiles (R10 measured 72.1us), Phase-A flush slimmed:
// truncating bf16 pack (v_perm only; the 2 RNE adds dropped — A-operand only).
// ---------------------------------------------------------------------------
template <int FOUT, bool RELU>
__global__ __launch_bounds__(1024, 8) void layer_kernel(
    const unsigned int* __restrict__ Xb2,        // [N][64] bf16 dword pairs
    const int* __restrict__ rs8,                 // [NB8+1]
    const float* __restrict__ inv8,              // [NB8] 1/max(cnt,1)
    const unsigned short* __restrict__ csr_src,  // [E] src ids sorted by (dst,rel)
    const unsigned short* __restrict__ Wpack,    // [NCT][36][64][8]
    const float* __restrict__ bias,
    void* __restrict__ Yout)
{
    __shared__ __align__(16) unsigned short Abuf[32][A_STRIDE];   // 74,240 B

    int tid = threadIdx.x;
    int wave = tid >> 6, lane = tid & 63;
    int l15 = lane & 15;
    int node0 = blockIdx.x * 32;

    // ---------------- Phase A: 2 nodes/wave as one 16-segment stream
    {
        int gn0 = node0 + wave * 2;
        unsigned int* row0 = (unsigned int*)&Abuf[wave * 2][0];
        unsigned int* row1 = (unsigned int*)&Abuf[wave * 2 + 1][0];

        int bl = lane <= 16 ? lane : 16;
        int bidx = gn0 * 8 + bl; if (bidx > NB8) bidx = NB8;       // tail clamp
        int bv = rs8[bidx];                          // lanes 0..16: segment bounds
        int iidx = gn0 * 8 + l15; if (iidx > NB8 - 1) iidx = NB8 - 1;
        int invi = ((const int*)inv8)[iidx];         // lanes 0..15: inv counts
        unsigned sidx0 = (unsigned)(gn0 < N_NODES - 1 ? gn0 : N_NODES - 1);
        unsigned int self0 = Xb2[(sidx0 << 6) | lane];
        unsigned int self1 = Xb2[((sidx0 + 1) << 6) | lane];

        int e     = __builtin_amdgcn_readlane(bv, 0);
        int e_end = __builtin_amdgcn_readlane(bv, 16);

        row0[lane] = self0;
        row1[lane] = self1;

        int r = 0;                                    // segment 0..15
        int be = __builtin_amdgcn_readlane(bv, 1);
        f32x2 av = (f32x2){0.f, 0.f};

#define FLUSH_R()                                                              \
        do {                                                                   \
            float iv_ = bitsf(__builtin_amdgcn_readlane(invi, r));             \
            unsigned ux_ = fbits(av.x * iv_);                                  \
            unsigned uy_ = fbits(av.y * iv_);                                  \
            unsigned pk_ = __builtin_amdgcn_perm(uy_, ux_, 0x07060302u);       \
            unsigned int* rw_ = (r < 8) ? row0 : row1;                         \
            rw_[(1 + (r & 7)) * 64 + lane] = pk_;                              \
            av = (f32x2){0.f, 0.f}; r++;                                       \
            be = __builtin_amdgcn_readlane(bv, r + 1 <= 16 ? r + 1 : 16);      \
        } while (0)

        if (e < e_end) {
            int e1m = e_end - 1;
            int ma = e + lane; if (ma > e1m) ma = e1m;
            unsigned int mv = csr_src[ma];             // 64-wide meta window
            int wbase = e;
            while (e < e_end) {
                int bn = e_end - e; if (bn > 16) bn = 16;
                int koff = e - wbase;                  // 0,16,32,48
                int sc[16];
#pragma unroll
                for (int k = 0; k < 16; k++)
                    sc[k] = __builtin_amdgcn_readlane((int)mv, koff + k);
                unsigned int xp[16];
#pragma unroll
                for (int k = 0; k < 16; k++)
                    xp[k] = Xb2[((unsigned)sc[k] << 6) | lane];
                int en = e + bn;
                if (koff + bn == 64 && en < e_end) {   // window exhausted
                    int mb = en + lane; if (mb > e1m) mb = e1m;
                    mv = csr_src[mb];
                    wbase = en;
                }
#pragma unroll
                for (int k = 0; k < 16; k++) {
                    if (k < bn) {                      // bn is wave-uniform
                        int ec = e + k;
                        while (ec >= be) FLUSH_R();
                        av += (f32x2){bflo2f(xp[k]), bfhi2f(xp[k])};
                    }
                }
                e = en;
            }
        }
        while (r < 16) FLUSH_R();
#undef FLUSH_R
    }
    __syncthreads();

    // ---------------- Phase B
    int quad = lane >> 4, l16 = lane & 15;
    if constexpr (FOUT == 128) {
        int ct = wave & 7;
        int half = wave >> 3;
        int node0h = node0 + half * 16;
        f32x4 acc = (f32x4){0.f, 0.f, 0.f, 0.f};
        const unsigned short* arow = &Abuf[half * 16 + l16][0];
        for (int ks = 0; ks < KSTEPS; ks++) {
            short8 b = *(const short8*)(Wpack + (((size_t)ct * KSTEPS + ks) * 64 + lane) * 8);
            short8 a = *(const short8*)(arow + ks * 32 + quad * 8);
            acc = __builtin_amdgcn_mfma_f32_16x16x32_bf16(a, b, acc, 0, 0, 0);
        }
        unsigned short* Yb = (unsigned short*)Yout;
        int h = ct * 16 + l16;
        float bvs = bias[h];
#pragma unroll
        for (int r4 = 0; r4 < 4; r4++) {
            int node = node0h + quad * 4 + r4;
            if (node < N_NODES) {
                float v = acc[r4] + bvs;
                if (RELU) v = v > 0.f ? v : 0.f;
                Yb[(size_t)node * 128 + h] = f2bf(v);
            }
        }
    } else {
        // FOUT == 16: per half, 8-way K-split + LDS reduce (red aliases Abuf)
        int half = wave >> 3, w8 = wave & 7;
        int ks0 = w8 * 4 + (w8 < 4 ? w8 : 4);
        int ksn = (w8 < 4) ? 5 : 4;
        f32x4 acc = (f32x4){0.f, 0.f, 0.f, 0.f};
        const unsigned short* arow = &Abuf[half * 16 + l16][0];
        for (int ks = ks0; ks < ks0 + ksn; ks++) {
            short8 b = *(const short8*)(Wpack + ((size_t)ks * 64 + lane) * 8);
            short8 a = *(const short8*)(arow + ks * 32 + quad * 8);
            acc = __builtin_amdgcn_mfma_f32_16x16x32_bf16(a, b, acc, 0, 0, 0);
        }
        __syncthreads();
        float* red = (float*)&Abuf[0][0];              // [2][8][64][4] = 16 KB
#pragma unroll
        for (int r4 = 0; r4 < 4; r4++)
            red[(((half * 8 + w8) * 64 + lane) << 2) + r4] = acc[r4];
        __syncthreads();
        if (tid < 512) {
            int half2 = tid >> 8, reg = (tid >> 6) & 3, l = tid & 63;
            float s = 0.f;
#pragma unroll
            for (int w = 0; w < 8; w++)
                s += red[(((half2 * 8 + w) * 64 + l) << 2) + reg];
            int node = node0 + half2 * 16 + ((l >> 4) << 2) + reg;
            int h = l & 15;
            if (node < N_NODES) {
                float v = s + bias[h];
                if (RELU) v = v > 0.f ? v : 0.f;
                ((float*)Yout)[(size_t)node * 16 + h] = v;
            }
        }
    }
}

// ---------------------------------------------------------------------------
extern "C" void kernel_launch(void* const* d_in, const int* in_sizes, int n_in,
                              void* d_out, int out_size, void* d_ws, size_t ws_size,
                              hipStream_t stream) {
    const float* x  = (const float*)d_in[0];
    const int*   ei = (const int*)d_in[1];
    const int*   et = (const int*)d_in[2];
    const float* w0 = (const float*)d_in[3];
    const float* r0 = (const float*)d_in[4];
    const float* b0 = (const float*)d_in[5];
    const float* w1 = (const float*)d_in[6];
    const float* r1 = (const float*)d_in[7];
    const float* b1 = (const float*)d_in[8];
    const float* w2 = (const float*)d_in[9];
    const float* r2 = (const float*)d_in[10];
    const float* b2 = (const float*)d_in[11];

    char* wsp = (char*)d_ws;
    size_t off = 0;
    auto alloc = [&](size_t bytes) -> void* {
        void* p = wsp + off;
        off += (bytes + 255) & ~(size_t)255;
        return p;
    };

    int* cnt    = (int*)alloc((size_t)NB8 * 4 + 64);   // flags ride at the end
    int* flags  = cnt + NB8;
    int* rs8    = (int*)alloc(((size_t)NB8 + 1) * 4);
    float* inv8 = (float*)alloc((size_t)NB8 * 4);
    int* rank   = (int*)alloc((size_t)N_EDGES * 4);
    int* tsum   = (int*)alloc((size_t)SCAN_T * 4);
    int* toff   = (int*)alloc((size_t)SCAN_T * 4);
    unsigned short* csr_src = (unsigned short*)alloc((size_t)N_EDGES * 2);
    unsigned short* Wp0 = (unsigned short*)alloc((size_t)8 * KSTEPS * 64 * 8 * 2);
    unsigned short* Wp1 = (unsigned short*)alloc((size_t)8 * KSTEPS * 64 * 8 * 2);
    unsigned short* Wp2 = (unsigned short*)alloc((size_t)1 * KSTEPS * 64 * 8 * 2);
    unsigned int* Xb = (unsigned int*)alloc((size_t)N_NODES * 64 * 4);
    unsigned int* H0 = (unsigned int*)alloc((size_t)N_NODES * 64 * 4);
    unsigned int* H1 = (unsigned int*)alloc((size_t)N_NODES * 64 * 4);

    hipMemsetAsync(cnt, 0, (size_t)NB8 * 4 + 64, stream);
    prep_rank_kernel<<<dim3(RANK_BLK + PREP_BLK), dim3(256), 0, stream>>>(
        ei, et, cnt, rank, x, Xb, r0, w0, Wp0, r1, w1, Wp1, r2, w2, Wp2);
    scanABC_kernel<<<dim3(SCAN_BLOCKS), dim3(256), 0, stream>>>(cnt, tsum, toff, rs8, inv8, flags);
    place_kernel<<<dim3((N_EDGES + 255) / 256), dim3(256), 0, stream>>>(ei, et, rank, rs8,
                                                                        csr_src, N_EDGES);

    layer_kernel<128, true ><<<dim3(NTILES32), dim3(1024), 0, stream>>>(
        Xb, rs8, inv8, csr_src, Wp0, b0, (void*)H0);
    layer_kernel<128, true ><<<dim3(NTILES32), dim3(1024), 0, stream>>>(
        H0, rs8, inv8, csr_src, Wp1, b1, (void*)H1);
    layer_kernel<16, false><<<dim3(NTILES32), dim3(1024), 0, stream>>>(
        H1, rs8, inv8, csr_src, Wp2, b2, d_out);
}